// Round 1
// baseline (560.667 us; speedup 1.0000x reference)
//
#include <hip/hip_runtime.h>

// Flow-warp bilinear resample with TF safe-gather + OOB masking.
// B=16, H=768, W=1024, C=4 (C=4 floats -> one float4 per pixel).
//
// Semantics (match JAX reference exactly):
//   warp_y = y + flow[...,0]; warp_x = x + flow[...,1]
//   x0=floor(wx), x1=ceil(wx)  (ceil, NOT x0+1 -- integer coords on the edge)
//   output = bilinear(taps) * mask, mask = all(0 <= warp <= dim-1)
// Inside the mask, floor/ceil taps are always in-bounds, so the safe-gather
// validity test reduces to the single mask branch; masked pixels are exact 0.
//
// V2 changes vs 551 µs baseline (flat 1D mapping):
//  1. 2D tiles: block = 64 wide x 16 tall (256 thr, 4 rows/thread, one wave
//     per 64-px row => flow/out stay fully coalesced). Gather taps of
//     co-resident threads now cluster in a compact ~184x136 px region
//     instead of a 256x1 strip smeared over ~120 source rows -> L1/L2
//     line reuse for the sigma=20px random taps.
//  2. Bijective XCD-chunked swizzle (12288 wg, 12288%8==0, chunk=1536):
//     each XCD's private L2 works a contiguous band of tiles (1536 tiles
//     = exactly 2 images) instead of round-robin interleaving -> no 8x
//     cross-L2 replication of the same source lines.
//  3. Non-temporal flow load + out store: both are streamed exactly once;
//     keep L1/L2/L3 capacity for the reused source gathers.
//  4. Hardcoded dims: runtime div/mod -> bit ops / compile-time magic mul.
//  5. 4 rows/thread: 16 independent tap loads in flight per thread
//     (latency hiding via ILP), flow/address arithmetic amortized.

typedef float v2f __attribute__((ext_vector_type(2)));
typedef float v4f __attribute__((ext_vector_type(4)));

constexpr int B = 16, H = 768, W = 1024;
constexpr int TX = 64;                 // tile width  (= 1 wave per row)
constexpr int TY = 16;                 // tile height
constexpr int RPT = 4;                 // rows per thread (256 thr = 4 waves)
constexpr int XT = W / TX;             // 16 x-tiles
constexpr int YT = H / TY;             // 48 y-tiles
constexpr int NWG = B * XT * YT;       // 12288 workgroups
constexpr int NXCD = 8;
constexpr int CHUNK = NWG / NXCD;      // 1536 (exact -> swizzle bijective)

__global__ __launch_bounds__(256) void warp_bilinear_kernel(
    const float* __restrict__ src,   // [B,H,W,4]
    const float* __restrict__ flow,  // [B,H,W,2]
    float* __restrict__ out)         // [B,H,W,4]
{
    // XCD-aware chunked swizzle: blocks dispatch round-robin across the 8
    // XCDs; give XCD k the contiguous tile range [k*CHUNK, (k+1)*CHUNK).
    unsigned orig = blockIdx.x;
    unsigned t = (orig & (NXCD - 1)) * CHUNK + (orig >> 3);

    int xt = t & (XT - 1);             // x-tile (fastest -> row-major bands)
    unsigned tt = t >> 4;              // XT == 16
    int yt = (int)(tt % YT);
    int b  = (int)(tt / YT);

    int tx = threadIdx.x & 63;         // x within tile
    int wv = threadIdx.x >> 6;         // wave id 0..3

    int x     = (xt << 6) + tx;
    int ybase = yt * TY + wv * RPT;

    const float4* sb = (const float4*)src + b * (H * W);
    const v2f*    fb = (const v2f*)flow;
    v4f*          ob = (v4f*)out;

    float xf = (float)x;

#pragma unroll
    for (int r = 0; r < RPT; ++r) {
        int y   = ybase + r;
        int pix = (b * H + y) * W + x;

        // flow: channel 0 -> y displacement, channel 1 -> x displacement
        v2f fl = __builtin_nontemporal_load(fb + pix);
        float wy = (float)y + fl.x;
        float wx = xf       + fl.y;

        v4f result = {0.f, 0.f, 0.f, 0.f};

        bool valid = (wy >= 0.f) & (wy <= (float)(H - 1)) &
                     (wx >= 0.f) & (wx <= (float)(W - 1));
        if (valid) {
            float fx = floorf(wx);
            float fy = floorf(wy);
            int x0 = (int)fx;
            int y0 = (int)fy;
            int x1 = (int)ceilf(wx);
            int y1 = (int)ceilf(wy);
            float wr = wx - fx;        // w_right
            float wd = wy - fy;        // w_down
            float wl = 1.f - wr;       // w_left
            float wu = 1.f - wd;       // w_up

            const float4* row0 = sb + y0 * W;
            const float4* row1 = sb + y1 * W;
            float4 g00 = row0[x0];
            float4 g01 = row0[x1];
            float4 g10 = row1[x0];
            float4 g11 = row1[x1];

            result.x = (g00.x * wl + g01.x * wr) * wu + (g10.x * wl + g11.x * wr) * wd;
            result.y = (g00.y * wl + g01.y * wr) * wu + (g10.y * wl + g11.y * wr) * wd;
            result.z = (g00.z * wl + g01.z * wr) * wu + (g10.z * wl + g11.z * wr) * wd;
            result.w = (g00.w * wl + g01.w * wr) * wu + (g10.w * wl + g11.w * wr) * wd;
        }

        __builtin_nontemporal_store(result, ob + pix);
    }
}

extern "C" void kernel_launch(void* const* d_in, const int* in_sizes, int n_in,
                              void* d_out, int out_size, void* d_ws, size_t ws_size,
                              hipStream_t stream) {
    const float* src  = (const float*)d_in[0];  // [B,H,W,4] fp32
    const float* flow = (const float*)d_in[1];  // [B,H,W,2] fp32
    float* out = (float*)d_out;

    warp_bilinear_kernel<<<NWG, 256, 0, stream>>>(src, flow, out);
}